// Round 1
// baseline (94.964 us; speedup 1.0000x reference)
//
#include <hip/hip_runtime.h>

// Sinkhorn loss, fully fused: one kernel, one block per batch (b=16), n=48x48=2304.
//
// lse factorization:  sum_j exp((u_i+v_j-C_ij)/eps) = e^{u_i/eps} * sum_j W_j * K_ij,
//   W_j = e^{v_j/eps},  K_ij = T[iy][jy]*T[ix][jx],  T[a][b] = exp(-((a-b)/48)^2/eps)
// Each reduction over j is two 48x48x48 contractions (separable), done in LDS.
// u, v, log_mu, log_nu live in per-thread registers (element 4t+q <-> thread t).

#define TPB 576  // 9 waves; 2304 outputs = 576 threads x float4

__device__ __forceinline__ float4 dot48(const float* __restrict__ A,
                                        const float* __restrict__ B,
                                        int r, int c0)
{
    // out[r][c0..c0+3] = sum_k A[r*48+k] * B[k*48 + c0..c0+3]
    const float* arow = A + r * 48;
    const float* bp   = B + c0;
    float4 acc = make_float4(0.f, 0.f, 0.f, 0.f);
#pragma unroll
    for (int k4 = 0; k4 < 12; ++k4) {
        const float4 a4 = *reinterpret_cast<const float4*>(arow + k4 * 4);
#pragma unroll
        for (int kk = 0; kk < 4; ++kk) {
            const float a = (kk == 0) ? a4.x : (kk == 1) ? a4.y : (kk == 2) ? a4.z : a4.w;
            const float4 bv = *reinterpret_cast<const float4*>(bp + (k4 * 4 + kk) * 48);
            acc.x = fmaf(a, bv.x, acc.x);
            acc.y = fmaf(a, bv.y, acc.y);
            acc.z = fmaf(a, bv.z, acc.z);
            acc.w = fmaf(a, bv.w, acc.w);
        }
    }
    return acc;
}

__global__ __launch_bounds__(TPB) void sinkhorn_kernel(const float* __restrict__ y,
                                                       const float* __restrict__ yt,
                                                       float* __restrict__ out)
{
    __shared__ __align__(16) float sT[2304];   // T[a][b] = exp(-dsq/eps)
    __shared__ __align__(16) float sTD[2304];  // T[a][b] * dsq
    __shared__ __align__(16) float sW[2304];   // exp(u/eps) or exp(v/eps)
    __shared__ __align__(16) float sP[2304];   // stage-1 intermediate
    __shared__ __align__(16) float sP2[2304];  // second intermediate (final cost)
    __shared__ float red[32];

    const int t  = threadIdx.x;
    const int b  = blockIdx.x;
    const int r  = t / 12;          // output row  (0..47)
    const int c0 = (t % 12) * 4;    // output cols (c0..c0+3); note r*48+c0 == 4*t
    const int wid  = t >> 6;
    const int lane = t & 63;

    const float EPS  = 0.01f;
    const float RINV = 100.0f;   // 1/eps
    const float ELSE = 1e-6f;

    // ---- build tables (identical y/x grids: arange(48)/48) ----
    for (int o = t; o < 2304; o += TPB) {
        int i = o / 48;
        int j = o - i * 48;
        float gi = (float)i / 48.0f;
        float gj = (float)j / 48.0f;
        float d  = gi - gj;
        float dsq = d * d;
        float e = expf(-dsq * RINV);
        sT[o]  = e;
        sTD[o] = e * dsq;
    }

    // ---- masses, log_mu / log_nu (this thread's 4 elements are y[b][4t..4t+3]) ----
    const float4 y4  = reinterpret_cast<const float4*>(y  + b * 2304)[t];
    const float4 yt4 = reinterpret_cast<const float4*>(yt + b * 2304)[t];
    float4 mx, my;
    mx.x = fminf(fmaxf(y4.x,  0.f), 1e9f) + 1e-9f;
    mx.y = fminf(fmaxf(y4.y,  0.f), 1e9f) + 1e-9f;
    mx.z = fminf(fmaxf(y4.z,  0.f), 1e9f) + 1e-9f;
    mx.w = fminf(fmaxf(y4.w,  0.f), 1e9f) + 1e-9f;
    my.x = fminf(fmaxf(yt4.x, 0.f), 1e9f) + 1e-9f;
    my.y = fminf(fmaxf(yt4.y, 0.f), 1e9f) + 1e-9f;
    my.z = fminf(fmaxf(yt4.z, 0.f), 1e9f) + 1e-9f;
    my.w = fminf(fmaxf(yt4.w, 0.f), 1e9f) + 1e-9f;

    float sx = mx.x + mx.y + mx.z + mx.w;
    float sy = my.x + my.y + my.z + my.w;
#pragma unroll
    for (int off = 32; off > 0; off >>= 1) {
        sx += __shfl_down(sx, off);
        sy += __shfl_down(sy, off);
    }
    if (lane == 0) { red[wid] = sx; red[16 + wid] = sy; }
    __syncthreads();
    if (t == 0) {
        float ax = 0.f, ay = 0.f;
#pragma unroll
        for (int w = 0; w < TPB / 64; ++w) { ax += red[w]; ay += red[16 + w]; }
        red[0] = ax; red[16] = ay;
    }
    __syncthreads();
    const float sumx = red[0], sumy = red[16];

    float4 lmu, lnu;
    lmu.x = logf(mx.x / sumx); lmu.y = logf(mx.y / sumx);
    lmu.z = logf(mx.z / sumx); lmu.w = logf(mx.w / sumx);
    lnu.x = logf(my.x / sumy); lnu.y = logf(my.y / sumy);
    lnu.z = logf(my.z / sumy); lnu.w = logf(my.w / sumy);

    float4 u = make_float4(0.f, 0.f, 0.f, 0.f);
    float4 v = make_float4(0.f, 0.f, 0.f, 0.f);
    reinterpret_cast<float4*>(sW)[t] = make_float4(1.f, 1.f, 1.f, 1.f);  // exp(v/eps), v=0
    __syncthreads();

    // ---- 5 Sinkhorn iterations ----
    for (int it = 0; it < 5; ++it) {
        // u-update: sW holds exp(v/eps)
        reinterpret_cast<float4*>(sP)[t] = dot48(sW, sT, r, c0);  // P[jy][ix]
        __syncthreads();
        {
            float4 S = dot48(sT, sP, r, c0);  // S_i = sum_j W_j K_ij
            float lse;
            lse = logf(expf(RINV * u.x) * S.x + ELSE); u.x = EPS * (lmu.x - lse) + u.x;
            lse = logf(expf(RINV * u.y) * S.y + ELSE); u.y = EPS * (lmu.y - lse) + u.y;
            lse = logf(expf(RINV * u.z) * S.z + ELSE); u.z = EPS * (lmu.z - lse) + u.z;
            lse = logf(expf(RINV * u.w) * S.w + ELSE); u.w = EPS * (lmu.w - lse) + u.w;
            reinterpret_cast<float4*>(sW)[t] =
                make_float4(expf(RINV * u.x), expf(RINV * u.y),
                            expf(RINV * u.z), expf(RINV * u.w));
        }
        __syncthreads();

        // v-update: sW holds exp(u/eps) (updated u)
        reinterpret_cast<float4*>(sP)[t] = dot48(sW, sT, r, c0);  // P[iy][jx]
        __syncthreads();
        {
            float4 S = dot48(sT, sP, r, c0);  // S_j = sum_i e^{u_i/eps} K_ij
            float lse;
            lse = logf(expf(RINV * v.x) * S.x + ELSE); v.x = EPS * (lnu.x - lse) + v.x;
            lse = logf(expf(RINV * v.y) * S.y + ELSE); v.y = EPS * (lnu.y - lse) + v.y;
            lse = logf(expf(RINV * v.z) * S.z + ELSE); v.z = EPS * (lnu.z - lse) + v.z;
            lse = logf(expf(RINV * v.w) * S.w + ELSE); v.w = EPS * (lnu.w - lse) + v.w;
            reinterpret_cast<float4*>(sW)[t] =
                make_float4(expf(RINV * v.x), expf(RINV * v.y),
                            expf(RINV * v.z), expf(RINV * v.w));
        }
        __syncthreads();
    }

    // ---- final cost: sum_ij pi_ij * C_ij, pi = e^{u/eps} W_j K_ij ----
    // K*C = TD[iy,jy]*T[ix,jx] + T[iy,jy]*TD[ix,jx]
    reinterpret_cast<float4*>(sP)[t]  = dot48(sW, sT,  r, c0);  // P1[jy][ix]
    reinterpret_cast<float4*>(sP2)[t] = dot48(sW, sTD, r, c0);  // P2[jy][ix]
    __syncthreads();
    float4 S1 = dot48(sTD, sP,  r, c0);
    float4 S2 = dot48(sT,  sP2, r, c0);
    float local =
        expf(RINV * u.x) * (S1.x + S2.x) +
        expf(RINV * u.y) * (S1.y + S2.y) +
        expf(RINV * u.z) * (S1.z + S2.z) +
        expf(RINV * u.w) * (S1.w + S2.w);

#pragma unroll
    for (int off = 32; off > 0; off >>= 1) local += __shfl_down(local, off);
    if (lane == 0) red[wid] = local;
    __syncthreads();
    if (t == 0) {
        float c = 0.f;
#pragma unroll
        for (int w = 0; w < TPB / 64; ++w) c += red[w];
        atomicAdd(out, c * (1.0f / 16.0f));
    }
}

extern "C" void kernel_launch(void* const* d_in, const int* in_sizes, int n_in,
                              void* d_out, int out_size, void* d_ws, size_t ws_size,
                              hipStream_t stream)
{
    (void)in_sizes; (void)n_in; (void)d_ws; (void)ws_size; (void)out_size;
    const float* y  = (const float*)d_in[0];
    const float* yt = (const float*)d_in[1];
    float* out = (float*)d_out;

    hipMemsetAsync(out, 0, sizeof(float), stream);
    sinkhorn_kernel<<<16, TPB, 0, stream>>>(y, yt, out);
}

// Round 2
// 73.259 us; speedup vs baseline: 1.2963x; 1.2963x over previous
//
#include <hip/hip_runtime.h>

// Sinkhorn loss, fully fused, MFMA bf16x3 (split-float) edition.
// One block per batch (b=16), n=48x48=2304, 5 iterations.
//
// All reductions are 48x48x48 contractions: S = T @ W @ T (T = separable
// Gaussian kernel table, symmetric). Each contraction = two stages of
// out = T @ X^T, computed as nine 16x16 MFMA tiles (one per wave, 9 waves).
// fp32 accuracy recovered via hi/lo bf16 split: A*B ~= Ah*Bh + Ah*Bl + Al*Bh.
//
// LDS matrices stored row-major, row stride 72 shorts (144 B):
//  - 16B-aligned b128 fragment reads, conflict-free (2 lanes/bank)
//  - cols 48..63 zero-padded (K padded to 64 for 2x mfma_16x16x32)

#define TPB 576      // 9 waves = 9 MFMA tiles of 16x16 = 48x48
#define STRIDE 72    // shorts per matrix row

typedef __attribute__((ext_vector_type(8))) short short8;
typedef __attribute__((ext_vector_type(4))) short short4v;
typedef __attribute__((ext_vector_type(4))) float f32x4;

__device__ __forceinline__ void splitb(float x, short& hi, short& lo) {
    union { float f; unsigned u; } a, h, l;
    a.f = x;
    h.u = a.u & 0xffff0000u;          // truncate to bf16 (lo captures residual)
    hi  = (short)(h.u >> 16);
    l.f = x - h.f;
    lo  = (short)(l.u >> 16);
}

__device__ __forceinline__ f32x4 mm16(short8 a, short8 b, f32x4 c) {
    return __builtin_amdgcn_mfma_f32_16x16x32_bf16(a, b, c, 0, 0, 0);
}

// 16x16 tile of A @ B over K=48 (padded to 64), bf16x3 emulation.
// A row-major at Ah/Al (A[m][k]), B^T row-major at Bh/Bl (B[k][n] = Bt[n][k]).
__device__ __forceinline__ f32x4 tile3(const short* Ah, const short* Al,
                                       const short* Bh, const short* Bl,
                                       int aOff, int bOff, f32x4 acc)
{
    short8 ah0 = *(const short8*)(Ah + aOff);
    short8 ah1 = *(const short8*)(Ah + aOff + 32);
    short8 al0 = *(const short8*)(Al + aOff);
    short8 al1 = *(const short8*)(Al + aOff + 32);
    short8 bh0 = *(const short8*)(Bh + bOff);
    short8 bh1 = *(const short8*)(Bh + bOff + 32);
    short8 bl0 = *(const short8*)(Bl + bOff);
    short8 bl1 = *(const short8*)(Bl + bOff + 32);
    f32x4 x = acc;
    f32x4 y = {0.f, 0.f, 0.f, 0.f};
    x = mm16(ah0, bh0, x);   // hi*hi
    y = mm16(ah1, bh1, y);
    x = mm16(ah0, bl0, x);   // hi*lo
    y = mm16(ah1, bl1, y);
    x = mm16(al0, bh0, x);   // lo*hi
    y = mm16(al1, bh1, y);
    return x + y;
}

__global__ __launch_bounds__(TPB) void sinkhorn_kernel(const float* __restrict__ y,
                                                       const float* __restrict__ yt,
                                                       float* __restrict__ out)
{
    __shared__ __align__(16) short sThi[48*STRIDE],  sTlo[48*STRIDE];   // T
    __shared__ __align__(16) short sTDhi[48*STRIDE], sTDlo[48*STRIDE];  // T*dsq
    __shared__ __align__(16) short sWhi[48*STRIDE],  sWlo[48*STRIDE];   // exp(./eps)
    __shared__ __align__(16) short sPhi[48*STRIDE],  sPlo[48*STRIDE];   // stage-1 out
    __shared__ __align__(16) float sS[2304];
    __shared__ float red[32];

    const int t    = threadIdx.x;
    const int b    = blockIdx.x;
    const int lane = t & 63;
    const int wid  = t >> 6;            // wave id 0..8
    const int tr   = wid / 3;           // tile row
    const int tc   = wid - tr * 3;      // tile col
    const int n15  = lane & 15;
    const int quad = lane >> 4;
    const int kq   = quad * 8;
    const int aOff   = (tr * 16 + n15) * STRIDE + kq;  // A-frag: A[m][kq..kq+7]
    const int bOff   = (tc * 16 + n15) * STRIDE + kq;  // B-frag: Bt[n][kq..kq+7]
    const int prBase = tr * 16 + quad * 4;             // C/D row base
    const int pn     = tc * 16 + n15;                  // C/D col
    const int wOffB  = (t / 12) * STRIDE + (t % 12) * 4;  // elementwise W write

    const float EPS = 0.01f, RINV = 100.0f;

    // ---- init: zero W/P (incl. K-padding), build T / TD hi+lo ----
    for (int i = t; i < 48 * STRIDE; i += TPB) {
        sWhi[i] = 0; sWlo[i] = 0; sPhi[i] = 0; sPlo[i] = 0;
        int a  = i / STRIDE;
        int bb = i - a * STRIDE;
        short th = 0, tl = 0, dh = 0, dl = 0;
        if (bb < 48) {
            float d   = (float)a / 48.0f - (float)bb / 48.0f;
            float dsq = d * d;
            float e   = __expf(-dsq * RINV);
            splitb(e, th, tl);
            splitb(e * dsq, dh, dl);
        }
        sThi[i] = th; sTlo[i] = tl; sTDhi[i] = dh; sTDlo[i] = dl;
    }

    // ---- masses, log_mu / log_nu (thread t owns elements 4t..4t+3) ----
    const f32x4 y4  = ((const f32x4*)(y  + b * 2304))[t];
    const f32x4 yt4 = ((const f32x4*)(yt + b * 2304))[t];
    float mx[4], my[4];
#pragma unroll
    for (int c = 0; c < 4; ++c) {
        mx[c] = fminf(fmaxf(y4[c],  0.f), 1e9f) + 1e-9f;
        my[c] = fminf(fmaxf(yt4[c], 0.f), 1e9f) + 1e-9f;
    }
    float sx = mx[0] + mx[1] + mx[2] + mx[3];
    float sy = my[0] + my[1] + my[2] + my[3];
#pragma unroll
    for (int off = 32; off > 0; off >>= 1) {
        sx += __shfl_down(sx, off);
        sy += __shfl_down(sy, off);
    }
    if (lane == 0) { red[wid] = sx; red[16 + wid] = sy; }
    __syncthreads();
    if (t == 0) {
        float ax = 0.f, ay = 0.f;
#pragma unroll
        for (int w = 0; w < TPB / 64; ++w) { ax += red[w]; ay += red[16 + w]; }
        red[0] = ax; red[16] = ay;
    }
    __syncthreads();
    const float rsx = 1.0f / red[0], rsy = 1.0f / red[16];

    float lmu_[4], lnu_[4];
#pragma unroll
    for (int c = 0; c < 4; ++c) {
        lmu_[c] = __logf(mx[c] * rsx);
        lnu_[c] = __logf(my[c] * rsy);
    }

    float u_[4]  = {0, 0, 0, 0}, v_[4]  = {0, 0, 0, 0};
    float wu_[4] = {1, 1, 1, 1}, wv_[4] = {1, 1, 1, 1};   // exp(u/eps), exp(v/eps)

    // W <- exp(v/eps) = 1
    {
        short4v oneh = {(short)0x3F80, (short)0x3F80, (short)0x3F80, (short)0x3F80};
        short4v zer  = {0, 0, 0, 0};
        *(short4v*)(sWhi + wOffB) = oneh;
        *(short4v*)(sWlo + wOffB) = zer;
    }
    __syncthreads();

    const f32x4 zz = {0.f, 0.f, 0.f, 0.f};

    auto do_upd = [&](float (&ab)[4], const float (&lm)[4], float (&wc)[4],
                      const f32x4& S4) {
        short4v h4, l4;
#pragma unroll
        for (int c = 0; c < 4; ++c) {
            float lse = __logf(wc[c] * S4[c] + 1e-6f);
            ab[c] = EPS * (lm[c] - lse) + ab[c];
            wc[c] = __expf(RINV * ab[c]);
            short hh, ll; splitb(wc[c], hh, ll);
            h4[c] = hh; l4[c] = ll;
        }
        *(short4v*)(sWhi + wOffB) = h4;
        *(short4v*)(sWlo + wOffB) = l4;
    };

    // ---- 10 half-iterations (u-update even, v-update odd) ----
    for (int half = 0; half < 10; ++half) {
        // stage 1: P^T = T @ W^T   (B-frags read W row-major)
        f32x4 p = tile3(sThi, sTlo, sWhi, sWlo, aOff, bOff, zz);
#pragma unroll
        for (int rg = 0; rg < 4; ++rg) {
            short h, l; splitb(p[rg], h, l);
            int o = (prBase + rg) * STRIDE + pn;
            sPhi[o] = h; sPlo[o] = l;
        }
        __syncthreads();
        // stage 2: S = T @ P      (B-frags read P^T row-major)
        f32x4 s = tile3(sThi, sTlo, sPhi, sPlo, aOff, bOff, zz);
#pragma unroll
        for (int rg = 0; rg < 4; ++rg)
            sS[(prBase + rg) * 48 + pn] = s[rg];
        __syncthreads();
        // elementwise: lse = log(e^{x/eps} S + 1e-6); update, write new W
        f32x4 S4 = *(const f32x4*)(sS + 4 * t);
        if ((half & 1) == 0) do_upd(u_, lmu_, wu_, S4);
        else                 do_upd(v_, lnu_, wv_, S4);
        __syncthreads();
    }

    // ---- final cost: sum_i e^{u_i/eps} * (TD@P + T@Q)_i,  P=Wv@T, Q=Wv@TD ----
    f32x4 p1 = tile3(sThi, sTlo, sWhi, sWlo, aOff, bOff, zz);     // P^T = T @ Wv^T
    f32x4 p2 = tile3(sTDhi, sTDlo, sWhi, sWlo, aOff, bOff, zz);   // Q^T = TD @ Wv^T
#pragma unroll
    for (int rg = 0; rg < 4; ++rg) {
        short h, l; splitb(p1[rg], h, l);
        int o = (prBase + rg) * STRIDE + pn;
        sPhi[o] = h; sPlo[o] = l;
    }
    __syncthreads();
    f32x4 sacc = tile3(sTDhi, sTDlo, sPhi, sPlo, aOff, bOff, zz); // S1 = TD @ P
    __syncthreads();                 // all S1 reads of sP done before overwrite
#pragma unroll
    for (int rg = 0; rg < 4; ++rg) {
        short h, l; splitb(p2[rg], h, l);
        int o = (prBase + rg) * STRIDE + pn;
        sPhi[o] = h; sPlo[o] = l;
    }
    __syncthreads();
    sacc = tile3(sThi, sTlo, sPhi, sPlo, aOff, bOff, sacc);       // + S2 = T @ Q
#pragma unroll
    for (int rg = 0; rg < 4; ++rg)
        sS[(prBase + rg) * 48 + pn] = sacc[rg];
    __syncthreads();

    f32x4 S4 = *(const f32x4*)(sS + 4 * t);
    float local = wu_[0] * S4[0] + wu_[1] * S4[1] + wu_[2] * S4[2] + wu_[3] * S4[3];
#pragma unroll
    for (int off = 32; off > 0; off >>= 1) local += __shfl_down(local, off);
    if (lane == 0) red[wid] = local;
    __syncthreads();
    if (t == 0) {
        float c = 0.f;
#pragma unroll
        for (int w = 0; w < TPB / 64; ++w) c += red[w];
        atomicAdd(out, c * (1.0f / 16.0f));
    }
}

extern "C" void kernel_launch(void* const* d_in, const int* in_sizes, int n_in,
                              void* d_out, int out_size, void* d_ws, size_t ws_size,
                              hipStream_t stream)
{
    (void)in_sizes; (void)n_in; (void)d_ws; (void)ws_size; (void)out_size;
    const float* y  = (const float*)d_in[0];
    const float* yt = (const float*)d_in[1];
    float* out = (float*)d_out;

    hipMemsetAsync(out, 0, sizeof(float), stream);
    sinkhorn_kernel<<<16, TPB, 0, stream>>>(y, yt, out);
}

// Round 3
// 68.257 us; speedup vs baseline: 1.3913x; 1.0733x over previous
//
#include <hip/hip_runtime.h>

// Sinkhorn loss, fully fused, MFMA edition v3.
// One block per batch (b=16), n=48x48=2304, 5 iterations, then a 16-float
// finisher kernel (no memset / atomics needed).
//
// S = T @ W @ T per half-iteration (T = separable Gaussian table, symmetric),
// as two 48x48x48 stages of nine 16x16 MFMA tiles (one per wave, 9 waves).
//  - T / TD A-fragments are compile-time-shaped constants per lane: computed
//    once into REGISTERS (hi/lo bf16 split, fp32-grade) — never touch LDS.
//  - W and P are stored bf16-RNE (single) in LDS; B-fragment reads only.
//  - u/v update done in MFMA C/D layout by the owning lane, no sS roundtrip,
//    2 barriers per half-iteration.
//  - 100*EPS == 1  =>  w' = w * mu / (w*S + 1e-6): no log/exp in the loop.

#define TPB 576      // 9 waves = 9 MFMA tiles of 16x16 = 48x48
#define STRIDE 72    // shorts per LDS matrix row (144 B, 16B-aligned frags)

typedef __attribute__((ext_vector_type(8))) short short8;
typedef __attribute__((ext_vector_type(4))) float f32x4;

__device__ __forceinline__ void splitb(float x, short& hi, short& lo) {
    union { float f; unsigned u; } a, h;
    a.f = x;
    h.u = a.u & 0xffff0000u;          // truncate; lo captures residual
    hi  = (short)(h.u >> 16);
    union { float f; unsigned u; } l;
    l.f = x - h.f;
    lo  = (short)(l.u >> 16);
}

__device__ __forceinline__ short bf16rne(float x) {
    union { float f; unsigned u; } a;
    a.f = x;
    unsigned r = a.u + 0x7fffu + ((a.u >> 16) & 1u);
    return (short)(r >> 16);
}

__device__ __forceinline__ f32x4 mm16(short8 a, short8 b, f32x4 c) {
    return __builtin_amdgcn_mfma_f32_16x16x32_bf16(a, b, c, 0, 0, 0);
}

__global__ __launch_bounds__(TPB) void sinkhorn_kernel(const float* __restrict__ y,
                                                       const float* __restrict__ yt,
                                                       float* __restrict__ partials)
{
    __shared__ __align__(16) short sW[48 * STRIDE];   // exp(./eps), bf16
    __shared__ __align__(16) short sP[48 * STRIDE];   // stage-1 out, bf16
    __shared__ __align__(16) short sP2[48 * STRIDE];  // final-cost second buf
    __shared__ float red[32];

    const int t    = threadIdx.x;
    const int b    = blockIdx.x;
    const int lane = t & 63;
    const int wid  = t >> 6;            // wave id 0..8
    const int tr   = wid / 3;           // tile row
    const int tc   = wid - tr * 3;      // tile col
    const int n15  = lane & 15;
    const int quad = lane >> 4;
    const int kq   = quad * 8;
    const int aRow = tr * 16 + n15;          // A-frag row (m)
    const int bBase = (tc * 16 + n15) * STRIDE;  // B-frag row base (n)
    const int prBase = tr * 16 + quad * 4;   // C/D row base
    const int pn     = tc * 16 + n15;        // C/D col
    const int wAddr  = prBase * STRIDE + pn; // scatter-write base (shorts)

    // ---- T / TD A-fragments in registers (hi/lo bf16 split) ----
    // A[m][k], lane holds k = kq..kq+7 (frag0) and kq+32..kq+39 (frag1).
    short8 Th0, Th1, Tl0, Tl1, Dh0, Dh1, Dl0, Dl1;
    {
        const float gm = (float)aRow / 48.0f;
#pragma unroll
        for (int kk = 0; kk < 8; ++kk) {
            int k0 = kq + kk;
            float d = gm - (float)k0 / 48.0f;
            float dsq = d * d;
            float e = __expf(-100.0f * dsq);
            short h, l;
            splitb(e, h, l);        Th0[kk] = h; Tl0[kk] = l;
            splitb(e * dsq, h, l);  Dh0[kk] = h; Dl0[kk] = l;
            int k1 = k0 + 32;
            if (k1 < 48) {
                float d1 = gm - (float)k1 / 48.0f;
                float q1 = d1 * d1;
                float e1 = __expf(-100.0f * q1);
                splitb(e1, h, l);       Th1[kk] = h; Tl1[kk] = l;
                splitb(e1 * q1, h, l);  Dh1[kk] = h; Dl1[kk] = l;
            } else {
                Th1[kk] = 0; Tl1[kk] = 0; Dh1[kk] = 0; Dl1[kk] = 0;
            }
        }
    }

    // ---- init LDS: W = 1.0 (bf16) in body, 0 in K-pad; P/P2 pads zeroed ----
    for (int i = t; i < 48 * STRIDE; i += TPB) {
        int col = i - (i / STRIDE) * STRIDE;
        sW[i]  = (col < 48) ? (short)0x3F80 : (short)0;
        sP[i]  = 0;
        sP2[i] = 0;
    }

    // ---- masses in C/D layout: lane owns elements (prBase+rg, pn) ----
    float mx[4], my[4];
#pragma unroll
    for (int rg = 0; rg < 4; ++rg) {
        int e = (prBase + rg) * 48 + pn;
        mx[rg] = fminf(fmaxf(y [b * 2304 + e], 0.f), 1e9f) + 1e-9f;
        my[rg] = fminf(fmaxf(yt[b * 2304 + e], 0.f), 1e9f) + 1e-9f;
    }
    float sx = mx[0] + mx[1] + mx[2] + mx[3];
    float sy = my[0] + my[1] + my[2] + my[3];
#pragma unroll
    for (int off = 32; off > 0; off >>= 1) {
        sx += __shfl_down(sx, off);
        sy += __shfl_down(sy, off);
    }
    if (lane == 0) { red[wid] = sx; red[16 + wid] = sy; }
    __syncthreads();
    if (t == 0) {
        float ax = 0.f, ay = 0.f;
#pragma unroll
        for (int w = 0; w < TPB / 64; ++w) { ax += red[w]; ay += red[16 + w]; }
        red[0] = ax; red[16] = ay;
    }
    __syncthreads();
    const float rsx = 1.0f / red[0], rsy = 1.0f / red[16];

    float mu_[4], nu_[4];
#pragma unroll
    for (int c = 0; c < 4; ++c) { mu_[c] = mx[c] * rsx; nu_[c] = my[c] * rsy; }

    float wu_[4] = {1, 1, 1, 1}, wv_[4] = {1, 1, 1, 1};  // exp(u/eps), exp(v/eps)

    const f32x4 zz = {0.f, 0.f, 0.f, 0.f};

    // ---- 10 half-iterations: u-update (even) / v-update (odd) ----
    for (int half = 0; half < 10; ++half) {
        // stage 1: P = T-tile @ W  (B-frags read sW row-major)
        {
            short8 b0 = *(const short8*)(sW + bBase + kq);
            short8 b1 = *(const short8*)(sW + bBase + kq + 32);
            f32x4 x = mm16(Th0, b0, zz);
            f32x4 yv = mm16(Th1, b1, zz);
            x  = mm16(Tl0, b0, x);
            yv = mm16(Tl1, b1, yv);
            f32x4 p = x + yv;
#pragma unroll
            for (int rg = 0; rg < 4; ++rg)
                sP[wAddr + rg * STRIDE] = bf16rne(p[rg]);
        }
        __syncthreads();
        // stage 2: S = T-tile @ P; update state in C/D layout; write new W
        {
            short8 b0 = *(const short8*)(sP + bBase + kq);
            short8 b1 = *(const short8*)(sP + bBase + kq + 32);
            f32x4 x = mm16(Th0, b0, zz);
            f32x4 yv = mm16(Th1, b1, zz);
            x  = mm16(Tl0, b0, x);
            yv = mm16(Tl1, b1, yv);
            f32x4 S = x + yv;
            float* wc       = ((half & 1) == 0) ? wu_ : wv_;
            const float* m_ = ((half & 1) == 0) ? mu_ : nu_;
#pragma unroll
            for (int c = 0; c < 4; ++c) {
                // 100*eps == 1:  w' = e^{u'/eps} = w * mu / (w*S + 1e-6)
                wc[c] = wc[c] * m_[c] / (wc[c] * S[c] + 1e-6f);
                sW[wAddr + c * STRIDE] = bf16rne(wc[c]);
            }
        }
        __syncthreads();
    }

    // ---- final cost: sum_i wu_i * (TD@(T@Wv) + T@(TD@Wv))_i ----
    {
        short8 b0 = *(const short8*)(sW + bBase + kq);
        short8 b1 = *(const short8*)(sW + bBase + kq + 32);
        f32x4 x1 = mm16(Th0, b0, zz), y1 = mm16(Th1, b1, zz);
        x1 = mm16(Tl0, b0, x1);  y1 = mm16(Tl1, b1, y1);
        f32x4 p1 = x1 + y1;                       // T @ Wv
        f32x4 x2 = mm16(Dh0, b0, zz), y2 = mm16(Dh1, b1, zz);
        x2 = mm16(Dl0, b0, x2);  y2 = mm16(Dl1, b1, y2);
        f32x4 p2 = x2 + y2;                       // TD @ Wv
#pragma unroll
        for (int rg = 0; rg < 4; ++rg) {
            sP [wAddr + rg * STRIDE] = bf16rne(p1[rg]);
            sP2[wAddr + rg * STRIDE] = bf16rne(p2[rg]);
        }
    }
    __syncthreads();
    float local;
    {
        short8 b0 = *(const short8*)(sP  + bBase + kq);
        short8 b1 = *(const short8*)(sP  + bBase + kq + 32);
        short8 c0 = *(const short8*)(sP2 + bBase + kq);
        short8 c1 = *(const short8*)(sP2 + bBase + kq + 32);
        f32x4 x = mm16(Dh0, b0, zz), yv = mm16(Dh1, b1, zz);
        x  = mm16(Dl0, b0, x);   yv = mm16(Dl1, b1, yv);
        x  = mm16(Th0, c0, x);   yv = mm16(Th1, c1, yv);
        x  = mm16(Tl0, c0, x);   yv = mm16(Tl1, c1, yv);
        f32x4 S = x + yv;
        local = wu_[0] * S[0] + wu_[1] * S[1] + wu_[2] * S[2] + wu_[3] * S[3];
    }
#pragma unroll
    for (int off = 32; off > 0; off >>= 1) local += __shfl_down(local, off);
    if (lane == 0) red[wid] = local;
    __syncthreads();
    if (t == 0) {
        float c = 0.f;
#pragma unroll
        for (int w = 0; w < TPB / 64; ++w) c += red[w];
        partials[b] = c;
    }
}

__global__ void finish_kernel(const float* __restrict__ partials,
                              float* __restrict__ out)
{
    int l = threadIdx.x;
    float v = (l < 16) ? partials[l] : 0.f;
#pragma unroll
    for (int off = 8; off > 0; off >>= 1) v += __shfl_down(v, off);
    if (l == 0) out[0] = v * (1.0f / 16.0f);
}

extern "C" void kernel_launch(void* const* d_in, const int* in_sizes, int n_in,
                              void* d_out, int out_size, void* d_ws, size_t ws_size,
                              hipStream_t stream)
{
    (void)in_sizes; (void)n_in; (void)ws_size; (void)out_size;
    const float* y  = (const float*)d_in[0];
    const float* yt = (const float*)d_in[1];
    float* partials = (float*)d_ws;
    float* out      = (float*)d_out;

    sinkhorn_kernel<<<16, TPB, 0, stream>>>(y, yt, partials);
    finish_kernel<<<1, 64, 0, stream>>>(partials, out);
}